// Round 1
// 1639.379 us; speedup vs baseline: 1.0017x; 1.0017x over previous
//
#include <hip/hip_runtime.h>

#define BB 2048
#define SS 200
#define HH 512
#define MTOT (BB*SS)   // 409600

typedef __attribute__((ext_vector_type(4))) float  f32x4;
typedef __attribute__((ext_vector_type(8))) __bf16 bf16x8;
typedef __attribute__((ext_vector_type(4))) short  short4v;

static __device__ __forceinline__ unsigned short f2bf(float f) {
    union { float f; unsigned int u; } v; v.f = f;
    unsigned int r = v.u + 0x7FFFu + ((v.u >> 16) & 1u);   // RNE
    return (unsigned short)(r >> 16);
}

static __device__ __forceinline__ float tanh_fast(float x) {
    // tanh(x) = 1 - 2/(e^{2x}+1); saturates correctly for |x| large (exp->inf/0)
    float e = __expf(2.0f * x);
    return 1.0f - 2.0f * __builtin_amdgcn_rcpf(e + 1.0f);
}

// ---------------- K0: Ur fp32 -> bf16 ----------------
__global__ __launch_bounds__(256) void k0_cvt(const float* __restrict__ Ur,
                                              unsigned short* __restrict__ Ur16) {
    int i = (blockIdx.x * 256 + threadIdx.x) * 4;
    f32x4 f = *(const f32x4*)(Ur + i);
    short4v q;
    q.x = (short)f2bf(f.x); q.y = (short)f2bf(f.y);
    q.z = (short)f2bf(f.z); q.w = (short)f2bf(f.w);
    *(short4v*)(Ur16 + i) = q;
}

// ---------------- K1: l[b,o] = sum_k last[b,k]*Wr[o,k] ----------------
// grid 512, 4 b's per block
__global__ __launch_bounds__(256) void k1_l(const float* __restrict__ last,
                                            const float* __restrict__ Wr,
                                            float* __restrict__ lbuf) {
    __shared__ __align__(16) float ll[4 * 516];
    const int t  = threadIdx.x;
    const int b0 = blockIdx.x * 4;
    #pragma unroll
    for (int i = 0; i < 8; ++i) {
        int idx = t + i * 256;
        int bl = idx >> 9, c = idx & 511;
        ll[bl * 516 + c] = last[(size_t)(b0 + bl) * HH + c];
    }
    __syncthreads();
    const int bl = t & 3;
    const int ob = t >> 2;               // 0..63
    const float* lr = ll + bl * 516;
    #pragma unroll
    for (int g = 0; g < 2; ++g) {
        float acc0 = 0.f, acc1 = 0.f, acc2 = 0.f, acc3 = 0.f;
        const f32x4* w0 = (const f32x4*)(Wr + (size_t)(ob + (g*4+0)*64) * HH);
        const f32x4* w1 = (const f32x4*)(Wr + (size_t)(ob + (g*4+1)*64) * HH);
        const f32x4* w2 = (const f32x4*)(Wr + (size_t)(ob + (g*4+2)*64) * HH);
        const f32x4* w3 = (const f32x4*)(Wr + (size_t)(ob + (g*4+3)*64) * HH);
        #pragma unroll 4
        for (int k = 0; k < 128; ++k) {
            f32x4 lv = *(const f32x4*)(lr + k * 4);
            f32x4 a = w0[k]; acc0 += a.x*lv.x + a.y*lv.y + a.z*lv.z + a.w*lv.w;
            f32x4 b = w1[k]; acc1 += b.x*lv.x + b.y*lv.y + b.z*lv.z + b.w*lv.w;
            f32x4 c = w2[k]; acc2 += c.x*lv.x + c.y*lv.y + c.z*lv.z + c.w*lv.w;
            f32x4 d = w3[k]; acc3 += d.x*lv.x + d.y*lv.y + d.z*lv.z + d.w*lv.w;
        }
        float* dst = lbuf + (size_t)(b0 + bl) * HH + ob;
        dst[(g*4+0)*64] = acc0; dst[(g*4+1)*64] = acc1;
        dst[(g*4+2)*64] = acc2; dst[(g*4+3)*64] = acc3;
    }
}

// ---------------- K2: scores[m] = sum_n tanh(A[m,:]@Ur[n,:] + l[b,n]) * v[n] ----
// BM=64 rows per block, full N=512 (4 waves x 128 cols), BK=64, mfma 16x16x32 bf16
// v2: LDS double-buffer + 1-deep register prefetch, ONE barrier per K-step.
//     Prefetch is issued AFTER the barrier so the compiler's vmcnt(0) drain at
//     s_barrier never waits on it; the load flies under the 64-MFMA phase and is
//     consumed at the next iteration's convert.
__global__ __launch_bounds__(256, 2) void k2_scores(const float* __restrict__ A,
                                                    const unsigned short* __restrict__ Ur16,
                                                    const float* __restrict__ lbuf,
                                                    const float* __restrict__ Vre,
                                                    float* __restrict__ scores) {
    __shared__ __align__(16) unsigned short Atile[2][64 * 72];  // 144B row stride (pad)
    __shared__ float red[4 * 64];

    const int t    = threadIdx.x;
    const int wave = t >> 6;
    const int lane = t & 63;
    const int quad = lane >> 4;
    const int l15  = lane & 15;
    const int m0   = blockIdx.x * 64;

    f32x4 acc[4][8];
    #pragma unroll
    for (int mt = 0; mt < 4; ++mt)
        #pragma unroll
        for (int nt = 0; nt < 8; ++nt)
            acc[mt][nt] = (f32x4){0.f, 0.f, 0.f, 0.f};

    const int srow = t >> 2;   // 0..63
    const int sseg = t & 3;    // 0..3
    const float* gA = A + (size_t)(m0 + srow) * HH + sseg * 4;

    const unsigned short* bptr = Ur16 + (size_t)(wave * 128 + l15) * HH + quad * 8;

    // prologue: prefetch kc=0
    f32x4 f[4];
    #pragma unroll
    for (int i = 0; i < 4; ++i) f[i] = *(const f32x4*)(gA + 0 * 64 + i * 16);

    #pragma unroll 1
    for (int kc = 0; kc < 8; ++kc) {
        // convert current prefetch and store to this step's LDS buffer
        unsigned short* wptr = &Atile[kc & 1][srow * 72 + sseg * 4];
        #pragma unroll
        for (int i = 0; i < 4; ++i) {
            short4v q;
            q.x = (short)f2bf(f[i].x); q.y = (short)f2bf(f[i].y);
            q.z = (short)f2bf(f[i].z); q.w = (short)f2bf(f[i].w);
            *(short4v*)(wptr + i * 16) = q;
        }
        __syncthreads();   // publishes buf[kc&1]; also fences readers of buf[kc&1] from step kc-2

        // issue next A-tile loads AFTER the barrier: they overlap the MFMA phase
        if (kc != 7) {
            #pragma unroll
            for (int i = 0; i < 4; ++i)
                f[i] = *(const f32x4*)(gA + (kc + 1) * 64 + i * 16);
        }

        const unsigned short* aptr = &Atile[kc & 1][l15 * 72 + quad * 8];
        #pragma unroll
        for (int ks = 0; ks < 2; ++ks) {
            bf16x8 af[4], bfr[8];
            #pragma unroll
            for (int mt = 0; mt < 4; ++mt)
                af[mt] = *(const bf16x8*)(aptr + mt * 16 * 72 + ks * 32);
            #pragma unroll
            for (int nt = 0; nt < 8; ++nt)
                bfr[nt] = *(const bf16x8*)(bptr + nt * 16 * HH + kc * 64 + ks * 32);
            #pragma unroll
            for (int nt = 0; nt < 8; ++nt)
                #pragma unroll
                for (int mt = 0; mt < 4; ++mt)
                    acc[mt][nt] = __builtin_amdgcn_mfma_f32_16x16x32_bf16(
                        af[mt], bfr[nt], acc[mt][nt], 0, 0, 0);
        }
    }

    // epilogue: tanh + v-dot, reduce over cols
    float vv[8];
    #pragma unroll
    for (int nt = 0; nt < 8; ++nt) vv[nt] = Vre[wave * 128 + nt * 16 + l15];

    #pragma unroll
    for (int mt = 0; mt < 4; ++mt) {
        #pragma unroll
        for (int r = 0; r < 4; ++r) {
            int m = m0 + mt * 16 + quad * 4 + r;
            int b = m / SS;
            const float* lrow = lbuf + (size_t)b * HH + wave * 128 + l15;
            float rs = 0.f;
            #pragma unroll
            for (int nt = 0; nt < 8; ++nt) {
                float x = acc[mt][nt][r] + lrow[nt * 16];
                rs += tanh_fast(x) * vv[nt];
            }
            rs += __shfl_xor(rs, 1);
            rs += __shfl_xor(rs, 2);
            rs += __shfl_xor(rs, 4);
            rs += __shfl_xor(rs, 8);
            if (l15 == 0) red[wave * 64 + mt * 16 + quad * 4 + r] = rs;
        }
    }
    __syncthreads();
    if (t < 64) scores[m0 + t] = red[t] + red[64 + t] + red[128 + t] + red[192 + t];
}

// ---------------- K3: softmax over S, ctx, logits, final softmax --------------
__global__ __launch_bounds__(256) void k3_out(const float* __restrict__ mem,
                                              const float* __restrict__ scores,
                                              const float* __restrict__ Wre,
                                              float* __restrict__ out) {
    __shared__ float attn[SS];
    __shared__ __align__(16) f32x4 ctx4[128];
    __shared__ float red[8];

    const int b = blockIdx.x;
    const int t = threadIdx.x;
    const int wv = t >> 6;

    float sv = (t < SS) ? scores[b * SS + t] : -1e30f;
    float mx = sv;
    #pragma unroll
    for (int off = 32; off; off >>= 1) mx = fmaxf(mx, __shfl_xor(mx, off));
    if ((t & 63) == 0) red[wv] = mx;
    __syncthreads();
    mx = fmaxf(fmaxf(red[0], red[1]), fmaxf(red[2], red[3]));
    float e = (t < SS) ? __expf(sv - mx) : 0.f;
    float sm = e;
    #pragma unroll
    for (int off = 32; off; off >>= 1) sm += __shfl_xor(sm, off);
    if ((t & 63) == 0) red[4 + wv] = sm;
    __syncthreads();
    sm = red[4] + red[5] + red[6] + red[7];
    if (t < SS) attn[t] = e / sm;
    __syncthreads();

    // ctx: thread covers 4 cols, half the threads take even s, half odd s
    const int p  = t >> 7;
    const int c4 = t & 127;
    f32x4 acc = (f32x4){0.f, 0.f, 0.f, 0.f};
    const f32x4* mem4 = (const f32x4*)mem;
    const size_t base = (size_t)b * SS * 128;
    #pragma unroll 4
    for (int s = p; s < SS; s += 2) {
        float a = attn[s];
        f32x4 v = mem4[base + (size_t)s * 128 + c4];
        acc.x += a * v.x; acc.y += a * v.y; acc.z += a * v.z; acc.w += a * v.w;
    }
    if (p == 0) ctx4[c4] = acc;
    __syncthreads();
    if (p == 1) {
        f32x4 c = ctx4[c4];
        c.x += acc.x; c.y += acc.y; c.z += acc.z; c.w += acc.w;
        ctx4[c4] = c;
    }
    __syncthreads();

    if (t < 128) {
        f32x4 c = ctx4[t];
        const f32x4* w4 = (const f32x4*)Wre;
        f32x4 w0 = w4[t], w1 = w4[128 + t];
        float p0 = c.x*w0.x + c.y*w0.y + c.z*w0.z + c.w*w0.w;
        float p1 = c.x*w1.x + c.y*w1.y + c.z*w1.z + c.w*w1.w;
        #pragma unroll
        for (int off = 32; off; off >>= 1) {
            p0 += __shfl_xor(p0, off);
            p1 += __shfl_xor(p1, off);
        }
        if ((t & 63) == 0) { red[wv * 2] = p0; red[wv * 2 + 1] = p1; }
    }
    __syncthreads();
    if (t == 0) {
        float l0 = red[0] + red[2], l1 = red[1] + red[3];
        float m2 = fmaxf(l0, l1);
        float e0 = __expf(l0 - m2), e1 = __expf(l1 - m2);
        float inv = 1.0f / (e0 + e1);
        out[b * 2]     = e0 * inv;
        out[b * 2 + 1] = e1 * inv;
    }
}

extern "C" void kernel_launch(void* const* d_in, const int* in_sizes, int n_in,
                              void* d_out, int out_size, void* d_ws, size_t ws_size,
                              hipStream_t stream) {
    const float* A    = (const float*)d_in[0];   // [B,S,H]
    const float* last = (const float*)d_in[1];   // [B,H]
    const float* Ur   = (const float*)d_in[2];   // [H,H]
    const float* Wr   = (const float*)d_in[3];   // [H,H]
    const float* Vre  = (const float*)d_in[4];   // [1,H]
    const float* Wre  = (const float*)d_in[5];   // [2,H]
    float* out = (float*)d_out;

    // workspace layout (needs 6,356,992 B)
    char* ws = (char*)d_ws;
    float* l_buf          = (float*)ws;                                    // B*H*4   = 4,194,304
    float* scores         = (float*)(ws + (size_t)BB * HH * 4);            // B*S*4   = 1,638,400
    unsigned short* Ur16  = (unsigned short*)(ws + (size_t)BB * HH * 4
                                                 + (size_t)BB * SS * 4);   // H*H*2   =   524,288

    k0_cvt   <<<(HH * HH / 4) / 256, 256, 0, stream>>>(Ur, Ur16);
    k1_l     <<<BB / 4,              256, 0, stream>>>(last, Wr, l_buf);
    k2_scores<<<MTOT / 64,           256, 0, stream>>>(A, Ur16, l_buf, Vre, scores);
    k3_out   <<<BB,                  256, 0, stream>>>(A, scores, Wre, out);
}